// Round 17
// baseline (710.287 us; speedup 1.0000x reference)
//
#include <hip/hip_runtime.h>

#define NDIM  2048
#define WAVES 32
#define BCOLS 2176            // 0..2048 valid + pad
#define SLOTS 2160            // 2112 steps + 48 staging overrun (2 blocks + 16)
#define ENCB  0x40000000
#define SENTV 0xFFFFFFFFFFFFFFFFull

typedef unsigned long long u64;

// Static scratch: prep kernels rewrite everything main relies on, every launch.
// g_S4[w][sidx][lane] = {exp theta[w*64+lane][sidx-lane][0..2], 0}
__device__ __align__(16) float4 g_S4[(size_t)WAVES * SLOTS * 64];
__device__ __align__(16) u64    g_B[(size_t)(WAVES+1) * BCOLS * 2]; // boundary handoff

__device__ __forceinline__ u64 ald(const u64* p) {
  return __hip_atomic_load(p, __ATOMIC_RELAXED, __HIP_MEMORY_SCOPE_AGENT);
}
__device__ __forceinline__ void ast(u64* p, u64 v) {
  __hip_atomic_store(p, v, __ATOMIC_RELAXED, __HIP_MEMORY_SCOPE_AGENT);
}
// shift-up-by-1 across the wave via DPP wave_shr1 (verified working).
__device__ __forceinline__ float shup1(float x) {
  int v = __builtin_amdgcn_update_dpp(0, __float_as_int(x), 0x138, 0xf, 0xf, false);
  return __int_as_float(v);
}
// DPP helper: max(m, dpp(m, CTRL)) with old=m (invalid lanes keep m).
template <int CTRL>
__device__ __forceinline__ float maxdpp(float m) {
  int v = __builtin_amdgcn_update_dpp(__float_as_int(m), __float_as_int(m),
                                      CTRL, 0xf, 0xf, false);
  return fmaxf(m, __int_as_float(v));
}
__device__ __forceinline__ int imax(int a, int b) { return a > b ? a : b; }

// global -> LDS direct DMA, 16B per lane (R9-verified mechanics).
typedef const __attribute__((address_space(1))) void GV;
typedef __attribute__((address_space(3)))       void LV;
__device__ __forceinline__ void gll16(const void* g, void* l) {
  __builtin_amdgcn_global_load_lds((GV*)g, (LV*)l, 16, 0, 0);
}

// ---------------- prep A: exp(theta) transposed into staircase order --------
__global__ void vit_prep_theta(const float* __restrict__ theta) {
  const int tid = blockIdx.x * blockDim.x + threadIdx.x;
  const int stride = gridDim.x * blockDim.x;
  const int total = WAVES * SLOTS * 64;
  for (int i = tid; i < total; i += stride) {
    const int l    = i & 63;
    const int rest = i >> 6;
    const int s    = rest % SLOTS;
    const int w    = rest / SLOTS;
    const int row  = w * 64 + l;
    const int col  = s - l;
    float4 r = make_float4(0.f, 0.f, 0.f, 0.f);
    if (col >= 0 && col < NDIM) {
      const float* tp = theta + ((size_t)row * NDIM + col) * 3;
      r.x = __expf(tp[0]); r.y = __expf(tp[1]); r.z = __expf(tp[2]);
    }
    g_S4[i] = r;
  }
}

// ---------------- prep B: sentinel/boundary init ---------------------------
__global__ void vit_prep_bnd() {
  const int tid = blockIdx.x * blockDim.x + threadIdx.x;
  const int stride = gridDim.x * blockDim.x;
  const int nb = (WAVES+1) * BCOLS;
  const u64 hi0 = ((u64)(unsigned)ENCB) << 32;   // (Y=0, e=0)
  for (int i = tid; i < nb; i += stride) {
    int w = i / BCOLS;
    int c = i - w * BCOLS;
    u64 lo, hi;
    if (c > NDIM)    { lo = 0ull; hi = hi0; }                                   // pad cols
    else if (w == 0) { lo = (c == 0) ? (u64)__float_as_uint(1.0f) : 0ull; hi = hi0; } // row 0
    else if (c == 0) { lo = 0ull; hi = hi0; }                                   // V[i,0] = -inf
    else             { lo = SENTV; hi = SENTV; }                                // to be produced
    ast(&g_B[(size_t)i*2],   lo);
    ast(&g_B[(size_t)i*2+1], hi);
  }
}

// per-dword sentinel test
__device__ __forceinline__ bool isbad(u64 lo, u64 hi) {
  return ((unsigned)lo == 0xFFFFFFFFu) || ((unsigned)(lo >> 32) == 0xFFFFFFFFu) ||
         ((unsigned)hi == 0xFFFFFFFFu) || ((unsigned)(hi >> 32) == 0xFFFFFFFFu);
}

// ---------------- main: 32 waves, striped wavefront, exp-space -------------
// Theta: TRIPLE-buffered LDS via global_load_lds (stage block k+2 at block k
// -> ~2 blocks of latency cover; no VGPR residency needed; no explicit fence:
// stripe prefetch is ordered BEFORE each gll batch, so validate's implicit
// s_waitcnt on the stripe value drains (in-order vmcnt) the current buffer's
// batch while leaving the newest batch in flight). Steps read theta through a
// 4-deep ds_read ring (16 VGPRs). STEP body / batched handoff / DPP rescale /
// ballot scale-prep are R14-verbatim (529us verified).
__global__ void __launch_bounds__(64, 1)
__attribute__((amdgpu_waves_per_eu(1, 1)))
vit_main(const float* __restrict__ A, float* __restrict__ out) {
  __shared__ float4 sT[3072];   // 3 bufs x 16 slots x 64 lanes = 48KB
  __shared__ float4 sB[16];     // handoff bounce (256B)
  const int lane = threadIdx.x;
  const int w    = blockIdx.x;
  const bool isL0 = (lane == 0);
  const int lsel = lane & 15;

  const float a00 = __expf(A[0]), a01 = __expf(A[1]), a02 = __expf(A[2]);
  const float a10 = __expf(A[3]), a11 = __expf(A[4]), a12 = __expf(A[5]);
  const float a20 = __expf(A[6]), a21 = __expf(A[7]), a22 = __expf(A[8]);

  const float4* tb4 = g_S4 + (size_t)w * SLOTS * 64 + lane;
  u64* bin  = g_B + (size_t)w     * BCOLS * 2;
  u64* bout = g_B + (size_t)(w+1) * BCOLS * 2;

  // state: own row col j-1 (p), row-above col j (u), row-above col j-1 (ud)
  float Mp=0.f,Xp=0.f,Yp=0.f, Mu=0.f,Xu=0.f,Yu=0.f, Mud=0.f,Xud=0.f,Yud=0.f;
  int e_w = 0;   // wave scale: registers hold value * 2^-e_w (wave-uniform)

  // ---- warmup: stripe preload FIRST, then gll batches, then spins (whose
  //      value-use drains all older vmcnt ops incl. both gll batches) ----
  u64* rpn;
  u64 cLo, cHi;
  {
    u64* rp0 = bin + (size_t)(2 + lsel) * 2;
    cLo = ald(rp0); cHi = ald(rp0 + 1);
    rpn = rp0 + 32;
  }
  #pragma unroll
  for (int u_ = 0; u_ < 16; ++u_)            // block 0 -> buf0
    gll16(tb4 + (size_t)u_ * 64, &sT[u_ * 64]);
  #pragma unroll
  for (int u_ = 0; u_ < 16; ++u_)            // block 1 -> buf1
    gll16(tb4 + (size_t)(16 + u_) * 64, &sT[1024 + u_ * 64]);

  // col 0 -> ud (prefilled, never sentinel)
  {
    u64 lo = ald(bin), hi = ald(bin + 1);
    while (isbad(lo, hi)) { __builtin_amdgcn_s_sleep(2); lo = ald(bin); hi = ald(bin+1); }
    if (isL0) {
      Mud = __uint_as_float((unsigned)lo);
      Xud = __uint_as_float((unsigned)(lo >> 32));
      Yud = __uint_as_float((unsigned)hi);
    }
  }
  // col 1 -> u (spin = pipeline fill)
  {
    u64 lo = ald(bin + 2), hi = ald(bin + 3);
    while (isbad(lo, hi)) { __builtin_amdgcn_s_sleep(8); lo = ald(bin+2); hi = ald(bin+3); }
    int ep = (int)((unsigned)(hi >> 32) - (unsigned)ENCB);
    int dd = ep - e_w;
    if (__builtin_amdgcn_readfirstlane(dd) > 48) { e_w = ep; dd = 0; } // states are zero
    if (isL0) {
      Mu = ldexpf(__uint_as_float((unsigned)lo), dd);
      Xu = ldexpf(__uint_as_float((unsigned)(lo >> 32)), dd);
      Yu = ldexpf(__uint_as_float((unsigned)hi), dd);
    }
  }
  __builtin_amdgcn_sched_barrier(0);

  unsigned cur = 0, nx1 = 1024, nx2 = 2048;   // LDS buf bases (float4 units)

// TM=1 -> terminal check (final block only). Theta from LDS ring reg DV.
#define STEPC(U, DV, TM)                                                       \
  {                                                                            \
    const int s = base + (U) + 1;           /* lane computes col j = s-lane */ \
    float mn = DV.x * fmaf(a02, Yud, fmaf(a01, Xud, a00*Mud));                 \
    float xn = DV.y * fmaf(a12, Yu,  fmaf(a11, Xu,  a10*Mu));                  \
    float yn = DV.z * fmaf(a22, Yp,  fmaf(a21, Xp,  a20*Mp));                  \
    /* handoff bounce: lane 63 -> LDS slot U (stored to global at block end) */\
    if (lane == 63)                                                            \
      sB[U] = make_float4(mn, xn, yn, __int_as_float(e_w + ENCB));             \
    if ((TM) && s == 2111 && w == 31 && lane == 63) {                          \
      out[0] = (log2f(mn + xn + yn) + (float)e_w) * 0.69314718055994531f;      \
    }                                                                          \
    /* boundary consume for col s+1: pre-scaled stripe, lane (U) -> SGPR */    \
    const float rM = __int_as_float(__builtin_amdgcn_readlane(__float_as_int(Mbf), (U))); \
    const float rX = __int_as_float(__builtin_amdgcn_readlane(__float_as_int(Xbf), (U))); \
    const float rY = __int_as_float(__builtin_amdgcn_readlane(__float_as_int(Ybf), (U))); \
    /* rotate */                                                               \
    Mud = Mu; Xud = Xu; Yud = Yu;                                              \
    const float sm = shup1(mn);                                                \
    const float sx = shup1(xn);                                                \
    const float sy = shup1(yn);                                                \
    Mu = isL0 ? rM : sm;                                                       \
    Xu = isL0 ? rX : sx;                                                       \
    Yu = isL0 ? rY : sy;                                                       \
    Mp = mn; Xp = xn; Yp = yn;                                                 \
  }
#define STEPR(U, DV, TM) STEPC(U, DV, TM) DV = sT[cur + ((U)+4)*64 + lane];

#define BLOCK(TM)                                                              \
  {                                                                            \
    /* ---- validate stripe (cols base+2 .. base+17). Its implicit waitcnt    \
            drains the gll batch for buffer `cur` (older, in-order vmcnt)     \
            while the newest batch stays in flight. ---- */                    \
    u64* rpc_ = rpn - 32;                                                      \
    bool bad_ = isbad(cLo, cHi);                                               \
    while (__ballot(bad_)) {                                                   \
      __builtin_amdgcn_s_sleep(1);                                             \
      cLo = ald(rpc_); cHi = ald(rpc_ + 1);                                    \
      bad_ = isbad(cLo, cHi);                                                  \
    }                                                                          \
    __builtin_amdgcn_sched_barrier(0);                                         \
    /* ---- scale prep: ballot-gated; injected dsl <= 0 always ---- */         \
    int dsl = ((int)(unsigned)(cHi >> 32) - ENCB) - e_w;                       \
    if (__ballot(dsl > 0)) {          /* rare adopt path */                    \
      int dm = dsl;                                                            \
      dm = imax(dm, __shfl_xor(dm, 1));                                        \
      dm = imax(dm, __shfl_xor(dm, 2));                                        \
      dm = imax(dm, __shfl_xor(dm, 4));                                        \
      dm = imax(dm, __shfl_xor(dm, 8));                                        \
      const int sh = -dm;                                                      \
      Mp = ldexpf(Mp,sh); Xp = ldexpf(Xp,sh); Yp = ldexpf(Yp,sh);              \
      Mu = ldexpf(Mu,sh); Xu = ldexpf(Xu,sh); Yu = ldexpf(Yu,sh);              \
      Mud= ldexpf(Mud,sh);Xud= ldexpf(Xud,sh);Yud= ldexpf(Yud,sh);             \
      e_w += dm; dsl -= dm;                                                    \
    }                                                                          \
    const float Mbf = ldexpf(__uint_as_float((unsigned)cLo), dsl);             \
    const float Xbf = ldexpf(__uint_as_float((unsigned)(cLo >> 32)), dsl);     \
    const float Ybf = ldexpf(__uint_as_float((unsigned)cHi), dsl);             \
    /* ---- stripe prefetch (block k+1) BEFORE the gll batch, so the next     \
            validate's wait does NOT drain that batch ---- */                  \
    u64 nLo = ald(rpn), nHi = ald(rpn + 1);                                    \
    rpn += 32;                                                                 \
    /* ---- stage block k+2 theta into buffer nx2 ---- */                      \
    {                                                                          \
      const float4* tn_ = tb4 + (size_t)(base + 32) * 64;                      \
      _Pragma("unroll")                                                        \
      for (int u_ = 0; u_ < 16; ++u_)                                          \
        gll16(tn_ + (size_t)u_ * 64, &sT[nx2 + u_ * 64]);                      \
    }                                                                          \
    __builtin_amdgcn_sched_barrier(0);                                         \
    /* ---- ds prologue: slots 0..3 of cur into the 4-deep ring ---- */        \
    float4 d0 = sT[cur + 0*64 + lane];                                         \
    float4 d1 = sT[cur + 1*64 + lane];                                         \
    float4 d2 = sT[cur + 2*64 + lane];                                         \
    float4 d3 = sT[cur + 3*64 + lane];                                         \
    /* ---- 16 steps ---- */                                                   \
    STEPR(0, d0, TM)  STEPR(1, d1, TM)  STEPR(2, d2, TM)  STEPR(3, d3, TM)     \
    STEPR(4, d0, TM)  STEPR(5, d1, TM)  STEPR(6, d2, TM)  STEPR(7, d3, TM)     \
    STEPR(8, d0, TM)  STEPR(9, d1, TM)  STEPR(10, d2, TM) STEPR(11, d3, TM)    \
    STEPC(12, d0, TM) STEPC(13, d1, TM) STEPC(14, d2, TM) STEPC(15, d3, TM)    \
    /* ---- batched handoff: lanes 0..15, 2 atomic u64 stores total ---- */    \
    {                                                                          \
      const int col_ = base - 62 + lane;                                       \
      if (lane < 16 && col_ >= 1) {                                            \
        float4 v = sB[lane];                                                   \
        u64 lo_ = ((u64)__float_as_uint(v.y) << 32) | __float_as_uint(v.x);    \
        u64 hi_ = ((u64)__float_as_uint(v.w) << 32) | __float_as_uint(v.z);    \
        u64* bO_ = bout + (size_t)col_ * 2;                                    \
        ast(bO_,     lo_);                                                     \
        ast(bO_ + 1, hi_);                                                     \
      }                                                                        \
    }                                                                          \
    /* ---- epoch rescale: DPP max tree + SALU exponent ---- */                \
    {                                                                          \
      float m = fmaxf(fmaxf(Mp, Xp), Yp);                                      \
      const int jl = base + 16 - lane;                                         \
      if (jl < 1 || jl > NDIM) m = 0.0f;                                       \
      m = maxdpp<0x111>(m);   /* row_shr:1  */                                 \
      m = maxdpp<0x112>(m);   /* row_shr:2  */                                 \
      m = maxdpp<0x114>(m);   /* row_shr:4  */                                 \
      m = maxdpp<0x118>(m);   /* row_shr:8  */                                 \
      m = maxdpp<0x142>(m);   /* row_bcast:15 */                               \
      m = maxdpp<0x143>(m);   /* row_bcast:31 -> lane 63 = wave max */         \
      const int mb = __builtin_amdgcn_readlane(__float_as_int(m), 63);         \
      int E = ((mb >> 23) & 0xFF) - 127;                                       \
      if (mb == 0) E = 0;                                                      \
      const int sh = -E;                                                       \
      Mp = ldexpf(Mp,sh); Xp = ldexpf(Xp,sh); Yp = ldexpf(Yp,sh);              \
      Mu = ldexpf(Mu,sh); Xu = ldexpf(Xu,sh); Yu = ldexpf(Yu,sh);              \
      Mud= ldexpf(Mud,sh);Xud= ldexpf(Xud,sh);Yud= ldexpf(Yud,sh);             \
      e_w += E;                                                                \
    }                                                                          \
    base += 16;                                                                \
    { unsigned t_ = cur; cur = nx1; nx1 = nx2; nx2 = t_; }                     \
    cLo = nLo; cHi = nHi;                                                      \
  }

  int base = 0;
  for (int it = 0; it < 131; ++it) { BLOCK(0) }
  BLOCK(1)   // block 131: terminal (s=2111 at U=14)
#undef BLOCK
#undef STEPR
#undef STEPC
}

extern "C" void kernel_launch(void* const* d_in, const int* in_sizes, int n_in,
                              void* d_out, int out_size, void* d_ws, size_t ws_size,
                              hipStream_t stream) {
  const float* theta = (const float*)d_in[0];
  const float* A     = (const float*)d_in[1];
  float* out = (float*)d_out;
  (void)in_sizes; (void)n_in; (void)out_size; (void)d_ws; (void)ws_size;
  vit_prep_theta<<<dim3(8192), dim3(256), 0, stream>>>(theta);
  vit_prep_bnd<<<dim3(256), dim3(256), 0, stream>>>();
  vit_main<<<dim3(WAVES), dim3(64), 0, stream>>>(A, out);
}